// Round 20
// baseline (93.905 us; speedup 1.0000x reference)
//
#include <hip/hip_runtime.h>

typedef __bf16 bf16_t;
typedef bf16_t bf16x8 __attribute__((ext_vector_type(8)));
typedef bf16_t bf16x4 __attribute__((ext_vector_type(4)));
typedef float f32x4 __attribute__((ext_vector_type(4)));

#define HW 4096
#define NC 256

__device__ __forceinline__ f32x4 mfma16(bf16x8 a, bf16x8 b, f32x4 c) {
  return __builtin_amdgcn_mfma_f32_16x16x32_bf16(a, b, c, 0, 0, 0);
}

// pack 8 f32 -> bf16x8 via v_cvt_pk_bf16_f32 (4 insts; elem order preserved)
__device__ __forceinline__ bf16x8 pack_bf16x8(float a0, float a1, float a2, float a3,
                                              float a4, float a5, float a6, float a7) {
  union { unsigned int u[4]; bf16x8 v; } r;
  asm("v_cvt_pk_bf16_f32 %0, %1, %2" : "=v"(r.u[0]) : "v"(a0), "v"(a1));
  asm("v_cvt_pk_bf16_f32 %0, %1, %2" : "=v"(r.u[1]) : "v"(a2), "v"(a3));
  asm("v_cvt_pk_bf16_f32 %0, %1, %2" : "=v"(r.u[2]) : "v"(a4), "v"(a5));
  asm("v_cvt_pk_bf16_f32 %0, %1, %2" : "=v"(r.u[3]) : "v"(a6), "v"(a7));
  return r.v;
}

// K-tile LDS bank swizzle: slot' = slot ^ swz(row) (verified conflict-free
// for both the staging writes and the permuted reads).
__device__ __forceinline__ int kswz(int m) {
  return ((m >> 1) & 1) | (((m >> 3) & 1) << 1);
}

// ---------------- kernel 0: convert weights fp32 -> bf16 ----------------
__global__ void cvt_w(const float* __restrict__ wq, const float* __restrict__ wk,
                      const float* __restrict__ wv, const float* __restrict__ wo,
                      bf16_t* __restrict__ dst) {
  int i = blockIdx.x * 256 + threadIdx.x;           // 65536 threads
  dst[i]          = (bf16_t)wq[i];
  dst[65536 + i]  = (bf16_t)wk[i];
  dst[131072 + i] = (bf16_t)wv[i];
  dst[196608 + i] = (bf16_t)wo[i];
}

// ---------------- kernel 1: QKV projection (o-tile 32, 2x TLP) ----------
// grid (64 p-tiles, 8 o-tiles, 2 b), block 256 (4 waves) -> 4 blocks/CU.
// Q/K: wave w owns p-strip w*16, t in 0..1 o-subtiles. V: wave w owns
// o-sub (w&1), p-subtiles {2*(w>>1)+j}. Double-buffered LDS + prefetch,
// one barrier/iter. D-layout: row = A-row (4hi+r), col = B-row (ln).
__global__ __launch_bounds__(256) void proj_qkv(
    const float* __restrict__ x, const float* __restrict__ flu,
    const bf16_t* __restrict__ Wq, const bf16_t* __restrict__ Wk,
    const bf16_t* __restrict__ Wv,
    const float* __restrict__ bq, const float* __restrict__ bk,
    const float* __restrict__ bv,
    bf16_t* __restrict__ Qb, bf16_t* __restrict__ Kb, bf16_t* __restrict__ Vb) {
  const int p0 = blockIdx.x * 64;
  const int o0 = blockIdx.y * 32;
  const int b  = blockIdx.z;
  const int tid = threadIdx.x;
  const int w = tid >> 6;
  const int lane = tid & 63;
  const int ln = lane & 15, hi = lane >> 4;

  __shared__ __align__(16) bf16_t lds_f[2][64][40];   // [buf][p][c], pad 32->40
  __shared__ __align__(16) bf16_t lds_x[2][64][40];

  f32x4 accQ[2] = {}, accK[2] = {}, accV[2] = {};
  const int vo = (w & 1) * 16;          // V o-sub base (local)
  const int vt0 = (w >> 1) * 2;         // V p-subtile base

  const int cl = tid >> 3;          // 0..31 local c
  const int pp = (tid & 7) * 4;     // 0..28 local p
  const float* fbase = flu + (size_t)b * NC * HW + p0;
  const float* xbase = x   + (size_t)b * NC * HW + p0;

  float4 fa, fb, xa, xb;
  {
    const float* fr = fbase + (size_t)cl * HW;
    const float* xr = xbase + (size_t)cl * HW;
    fa = *(const float4*)(fr + pp);
    fb = *(const float4*)(fr + pp + 32);
    xa = *(const float4*)(xr + pp);
    xb = *(const float4*)(xr + pp + 32);
  }
#define STORE_TILE(B)                                                        \
  {                                                                          \
    lds_f[B][pp + 0][cl] = (bf16_t)fa.x;  lds_f[B][pp + 1][cl] = (bf16_t)fa.y;  \
    lds_f[B][pp + 2][cl] = (bf16_t)fa.z;  lds_f[B][pp + 3][cl] = (bf16_t)fa.w;  \
    lds_f[B][pp + 32][cl] = (bf16_t)fb.x; lds_f[B][pp + 33][cl] = (bf16_t)fb.y; \
    lds_f[B][pp + 34][cl] = (bf16_t)fb.z; lds_f[B][pp + 35][cl] = (bf16_t)fb.w; \
    lds_x[B][pp + 0][cl] = (bf16_t)xa.x;  lds_x[B][pp + 1][cl] = (bf16_t)xa.y;  \
    lds_x[B][pp + 2][cl] = (bf16_t)xa.z;  lds_x[B][pp + 3][cl] = (bf16_t)xa.w;  \
    lds_x[B][pp + 32][cl] = (bf16_t)xb.x; lds_x[B][pp + 33][cl] = (bf16_t)xb.y; \
    lds_x[B][pp + 34][cl] = (bf16_t)xb.z; lds_x[B][pp + 35][cl] = (bf16_t)xb.w; \
  }
  STORE_TILE(0);
  __syncthreads();

#pragma unroll
  for (int it = 0; it < 8; ++it) {
    const int cur = it & 1;
    const int c0 = it * 32;
    if (it < 7) {  // prefetch next tile (hidden under compute)
      const float* fr = fbase + (size_t)(c0 + 32 + cl) * HW;
      const float* xr = xbase + (size_t)(c0 + 32 + cl) * HW;
      fa = *(const float4*)(fr + pp);
      fb = *(const float4*)(fr + pp + 32);
      xa = *(const float4*)(xr + pp);
      xb = *(const float4*)(xr + pp + 32);
    }

    bf16x8 af = *(const bf16x8*)&lds_f[cur][w * 16 + ln][hi * 8];
    bf16x8 ax = *(const bf16x8*)&lds_x[cur][w * 16 + ln][hi * 8];
    bf16x8 awv = *(const bf16x8*)(Wv + (size_t)(o0 + vo + ln) * NC + c0 + hi * 8);
#pragma unroll
    for (int t = 0; t < 2; ++t) {
      bf16x8 bwq = *(const bf16x8*)(Wq + (size_t)(o0 + t * 16 + ln) * NC + c0 + hi * 8);
      accQ[t] = mfma16(af, bwq, accQ[t]);
      bf16x8 bwk = *(const bf16x8*)(Wk + (size_t)(o0 + t * 16 + ln) * NC + c0 + hi * 8);
      accK[t] = mfma16(ax, bwk, accK[t]);
      bf16x8 bx = *(const bf16x8*)&lds_x[cur][(vt0 + t) * 16 + ln][hi * 8];
      accV[t] = mfma16(awv, bx, accV[t]);
    }

    if (it < 7) {
      STORE_TILE(cur ^ 1);
      __syncthreads();
    }
  }
#undef STORE_TILE

  // dk^-0.5 * log2(e): exp2-domain logits
  const float scale = 0.17677669529663687f * 1.4426950408889634f;
#pragma unroll
  for (int t = 0; t < 2; ++t) {
    int o = o0 + t * 16 + ln;
    int h = o >> 5, d = o & 31;
    float bqv = bq[o], bkv = bk[o];
#pragma unroll
    for (int r = 0; r < 4; ++r) {
      int p = p0 + w * 16 + hi * 4 + r;
      size_t idx = (((size_t)(b * 8 + h)) * HW + p) * 32 + d;
      Qb[idx] = (bf16_t)((accQ[t][r] + bqv) * scale);
      Kb[idx] = (bf16_t)(accK[t][r] + bkv);
    }
  }
#pragma unroll
  for (int t = 0; t < 2; ++t) {
    int p = p0 + (vt0 + t) * 16 + ln;
#pragma unroll
    for (int r = 0; r < 4; ++r) {
      int o = o0 + vo + hi * 4 + r;
      Vb[((size_t)b * NC + o) * HW + p] = (bf16_t)(accV[t][r] + bv[o]);
    }
  }
}

// ---------------- kernel 2: flash attention (in-block split-K, proven) ----
// Block = 4 waves / 64 q: half = w>>1 selects keys 0..2047 / 2048..4095;
// wq = w&1 selects q-subtile. Per-half K/V LDS staging; exact merge via
// LDS (no-max softmax => plain fp32 add). grid 1024 XCD-swizzled.
__global__ __launch_bounds__(256, 4) void attn_fwd(
    const bf16_t* __restrict__ Qb, const bf16_t* __restrict__ Kb,
    const bf16_t* __restrict__ Vb, bf16_t* __restrict__ AO) {
  // bijective XCD swizzle: 1024 blocks, each XCD gets 128 contiguous lids = 2 bh
  const int fid = blockIdx.x;
  const int lid = (fid & 7) * 128 + (fid >> 3);
  const int q0 = (lid & 63) * 64;
  const int bh = lid >> 6;
  const int b = bh >> 3, h = bh & 7;
  const int tid = threadIdx.x;
  const int w = tid >> 6, lane = tid & 63;
  const int half = w >> 1, wq = w & 1;
  const int ln = lane & 15, hi = lane >> 4;
  const int tid_h = tid & 127;

  __shared__ __align__(16) bf16_t Kt[2][2][2048];   // [half][buf][m*32+d'], swz
  __shared__ __align__(16) bf16_t Vt[2][2][2048];   // [half][buf][d*64+m'], swz

  const bf16_t* Qh = Qb + (size_t)bh * HW * 32;
  const bf16_t* Kh = Kb + (size_t)bh * HW * 32;
  const bf16_t* Vh = Vb + ((size_t)b * NC + h * 32) * HW;

  // B-frags of Q^T: lane holds Q[q0 + wq*32 + g*16 + ln][hi*8..+7]
  const int qb = q0 + wq * 32;
  const bf16x8 qf0 = *(const bf16x8*)(Qh + (size_t)(qb + ln) * 32 + hi * 8);
  const bf16x8 qf1 = *(const bf16x8*)(Qh + (size_t)(qb + 16 + ln) * 32 + hi * 8);

  f32x4 O[2][2] = {};           // O^T accum [g][dt], lane owns q-col ln
  f32x4 Lacc0 = {}, Lacc1 = {}; // ones-row denominators per g
  const bf16_t one = (bf16_t)1.0f;
  const bf16x8 ones = {one, one, one, one, one, one, one, one};

  // K staging (128 threads/half, 2x16B): K tile [64][32], swizzled slots
  const int kr = tid_h >> 1, ksp = (tid_h & 1) * 2;
  const int kofs0 = kr * 32 + ((ksp ^ kswz(kr)) * 8);
  const int kofs1 = kr * 32 + (((ksp + 1) ^ kswz(kr)) * 8);
  const bf16_t* kgp = Kh + (size_t)(half * 2048 + kr) * 32 + ksp * 8;

  // V staging (128 threads/half, 2x16B): V^T tile [32][64]
  const int vr = tid_h >> 2, vsp = (tid_h & 3) * 2;
  const int vofs0 = vr * 64 + ((vsp ^ (vr & 7)) * 8);
  const int vofs1 = vr * 64 + (((vsp + 1) ^ (vr & 7)) * 8);
  const bf16_t* vgp = Vh + (size_t)vr * HW + half * 2048 + vsp * 8;

  // permuted K read offsets (proven conflict-free under kswz)
  int kread[2][2];
  {
    const int F0 = 8 * (ln >> 2) + (ln & 3);
#pragma unroll
    for (int ch = 0; ch < 2; ++ch) {
#pragma unroll
      for (int j = 0; j < 2; ++j) {
        int row = ch * 32 + F0 + 4 * j;
        kread[ch][j] = row * 32 + ((hi ^ kswz(row)) * 8);
      }
    }
  }
  int vread[2][2];
#pragma unroll
  for (int dt = 0; dt < 2; ++dt)
#pragma unroll
    for (int ch = 0; ch < 2; ++ch)
      vread[dt][ch] = (dt * 16 + ln) * 64 + (((ch * 4 + hi) ^ (ln & 7)) * 8);

  // prologue: tile 0 staging regs
  bf16x8 kstA0 = *(const bf16x8*)kgp;
  bf16x8 kstA1 = *(const bf16x8*)(kgp + 8);
  bf16x8 vstA0 = *(const bf16x8*)vgp;
  bf16x8 vstA1 = *(const bf16x8*)(vgp + 8);
  bf16x8 kstB0, kstB1, vstB0, vstB1;

  auto compute = [&](const bf16_t* K_, const bf16_t* V_) {
    __builtin_amdgcn_s_setprio(1);
#pragma unroll
    for (int ch = 0; ch < 2; ++ch) {
      bf16x8 kf0 = *(const bf16x8*)&K_[kread[ch][0]];
      bf16x8 kf1 = *(const bf16x8*)&K_[kread[ch][1]];
      f32x4 z = {};
      f32x4 Sa0 = mfma16(kf0, qf0, z);
      f32x4 Sa1 = mfma16(kf1, qf0, z);
      f32x4 Sb0 = mfma16(kf0, qf1, z);
      f32x4 Sb1 = mfma16(kf1, qf1, z);
      float a0 = __builtin_amdgcn_exp2f(Sa0[0]), a1 = __builtin_amdgcn_exp2f(Sa0[1]);
      float a2 = __builtin_amdgcn_exp2f(Sa0[2]), a3 = __builtin_amdgcn_exp2f(Sa0[3]);
      float a4 = __builtin_amdgcn_exp2f(Sa1[0]), a5 = __builtin_amdgcn_exp2f(Sa1[1]);
      float a6 = __builtin_amdgcn_exp2f(Sa1[2]), a7 = __builtin_amdgcn_exp2f(Sa1[3]);
      float b0 = __builtin_amdgcn_exp2f(Sb0[0]), b1 = __builtin_amdgcn_exp2f(Sb0[1]);
      float b2 = __builtin_amdgcn_exp2f(Sb0[2]), b3 = __builtin_amdgcn_exp2f(Sb0[3]);
      float b4 = __builtin_amdgcn_exp2f(Sb1[0]), b5 = __builtin_amdgcn_exp2f(Sb1[1]);
      float b6 = __builtin_amdgcn_exp2f(Sb1[2]), b7 = __builtin_amdgcn_exp2f(Sb1[3]);
      bf16x8 pa = pack_bf16x8(a0, a1, a2, a3, a4, a5, a6, a7);
      bf16x8 pb = pack_bf16x8(b0, b1, b2, b3, b4, b5, b6, b7);
      Lacc0 = mfma16(ones, pa, Lacc0);
      Lacc1 = mfma16(ones, pb, Lacc1);
#pragma unroll
      for (int dt = 0; dt < 2; ++dt) {
        bf16x8 vf = *(const bf16x8*)&V_[vread[dt][ch]];
        O[0][dt] = mfma16(vf, pa, O[0][dt]);
        O[1][dt] = mfma16(vf, pb, O[1][dt]);
      }
    }
    __builtin_amdgcn_s_setprio(0);
  };

  for (int t = 0; t < 16; ++t) {
    // ---- even tile 2t ----
    {
      bf16_t* K0 = &Kt[half][0][0];
      bf16_t* V0 = &Vt[half][0][0];
      *(bf16x8*)&K0[kofs0] = kstA0;
      *(bf16x8*)&K0[kofs1] = kstA1;
      *(bf16x8*)&V0[vofs0] = vstA0;
      *(bf16x8*)&V0[vofs1] = vstA1;
    }
    __syncthreads();
    {  // prefetch tile 2t+1 (always valid: <= 31)
      kstB0 = *(const bf16x8*)(kgp + (size_t)(2 * t + 1) * 2048);
      kstB1 = *(const bf16x8*)(kgp + (size_t)(2 * t + 1) * 2048 + 8);
      vstB0 = *(const bf16x8*)(vgp + (2 * t + 1) * 64);
      vstB1 = *(const bf16x8*)(vgp + (2 * t + 1) * 64 + 8);
    }
    compute(&Kt[half][0][0], &Vt[half][0][0]);
    // ---- odd tile 2t+1 ----
    {
      bf16_t* K1 = &Kt[half][1][0];
      bf16_t* V1 = &Vt[half][1][0];
      *(bf16x8*)&K1[kofs0] = kstB0;
      *(bf16x8*)&K1[kofs1] = kstB1;
      *(bf16x8*)&V1[vofs0] = vstB0;
      *(bf16x8*)&V1[vofs1] = vstB1;
    }
    __syncthreads();
    if (t < 15) {  // prefetch tile 2t+2
      kstA0 = *(const bf16x8*)(kgp + (size_t)(2 * t + 2) * 2048);
      kstA1 = *(const bf16x8*)(kgp + (size_t)(2 * t + 2) * 2048 + 8);
      vstA0 = *(const bf16x8*)(vgp + (2 * t + 2) * 64);
      vstA1 = *(const bf16x8*)(vgp + (2 * t + 2) * 64 + 8);
    }
    compute(&Kt[half][1][0], &Vt[half][1][0]);
  }

  // ---- split-K merge (exact: no-max softmax => plain fp32 add) ----
  __syncthreads();                       // all K/V use done; safe to alias Kt
  float* MO = (float*)&Kt[0][0][0];      // [64 q][32 d], swizzled 4-slot cols
  float* ML = MO + 2048;                 // [2 wq][2 g][16 ln]
  if (half == 1) {
#pragma unroll
    for (int g = 0; g < 2; ++g) {
      int q = wq * 32 + g * 16 + ln;
#pragma unroll
      for (int dt = 0; dt < 2; ++dt) {
        int slot = dt * 4 + hi;
        *(f32x4*)&MO[q * 32 + ((slot ^ (ln & 7)) * 4)] = O[g][dt];
      }
    }
    if (hi == 0) { ML[(wq * 2 + 0) * 16 + ln] = Lacc0[0];
                   ML[(wq * 2 + 1) * 16 + ln] = Lacc1[0]; }
  }
  __syncthreads();
  if (half == 0) {
#pragma unroll
    for (int g = 0; g < 2; ++g) {
      int q = wq * 32 + g * 16 + ln;
      float l = (g ? Lacc1[0] : Lacc0[0]) + ML[(wq * 2 + g) * 16 + ln];
      float inv = 1.0f / l;
      const int p = q0 + q;
#pragma unroll
      for (int dt = 0; dt < 2; ++dt) {
        int slot = dt * 4 + hi;
        f32x4 o4 = O[g][dt] + *(const f32x4*)&MO[q * 32 + ((slot ^ (ln & 7)) * 4)];
        bf16x4 ov = {(bf16_t)(o4[0] * inv), (bf16_t)(o4[1] * inv),
                     (bf16_t)(o4[2] * inv), (bf16_t)(o4[3] * inv)};
        *(bf16x4*)(AO + ((size_t)b * HW + p) * NC + h * 32 + dt * 16 + hi * 4) = ov;
      }
    }
  }
}

// ---------------- kernel 3: output projection (p-tile 32, 2x TLP) --------
// grid (128 p-tiles, 4 o-tiles, 2 b), block 256 -> 4 blocks/CU. Register
// double-buffer over c0 (2x unrolled), acc[2].
__global__ __launch_bounds__(256) void proj_out(
    const bf16_t* __restrict__ AO, const bf16_t* __restrict__ Wo,
    const float* __restrict__ bo, float* __restrict__ out) {
  const int p0 = blockIdx.x * 32;
  const int o0 = blockIdx.y * 64;
  const int b  = blockIdx.z;
  const int tid = threadIdx.x;
  const int w = tid >> 6, lane = tid & 63;
  const int ln = lane & 15, hi = lane >> 4;

  const bf16_t* awp = Wo + (size_t)(o0 + w * 16 + ln) * NC + hi * 8;
  const bf16_t* bp0 = AO + ((size_t)b * HW + p0 + ln) * NC + hi * 8;

  f32x4 acc[2] = {};
  bf16x8 awA, awB, bA[2], bB[2];
  awA = *(const bf16x8*)awp;
#pragma unroll
  for (int t = 0; t < 2; ++t) bA[t] = *(const bf16x8*)(bp0 + (size_t)(t * 16) * NC);

#pragma unroll
  for (int it = 0; it < 8; it += 2) {
    {  // prefetch set B (c0 = (it+1)*32)
      int c1 = (it + 1) * 32;
      awB = *(const bf16x8*)(awp + c1);
#pragma unroll
      for (int t = 0; t < 2; ++t) bB[t] = *(const bf16x8*)(bp0 + (size_t)(t * 16) * NC + c1);
    }
#pragma unroll
    for (int t = 0; t < 2; ++t) acc[t] = mfma16(awA, bA[t], acc[t]);
    if (it + 2 < 8) {  // prefetch set A (c0 = (it+2)*32)
      int c2 = (it + 2) * 32;
      awA = *(const bf16x8*)(awp + c2);
#pragma unroll
      for (int t = 0; t < 2; ++t) bA[t] = *(const bf16x8*)(bp0 + (size_t)(t * 16) * NC + c2);
    }
#pragma unroll
    for (int t = 0; t < 2; ++t) acc[t] = mfma16(awB, bB[t], acc[t]);
  }

#pragma unroll
  for (int t = 0; t < 2; ++t) {
#pragma unroll
    for (int r = 0; r < 4; ++r) {
      int o = o0 + w * 16 + hi * 4 + r;
      out[((size_t)b * NC + o) * HW + p0 + t * 16 + ln] = acc[t][r] + bo[o];
    }
  }
}

// ---------------- launch ----------------
extern "C" void kernel_launch(void* const* d_in, const int* in_sizes, int n_in,
                              void* d_out, int out_size, void* d_ws, size_t ws_size,
                              hipStream_t stream) {
  const float* x   = (const float*)d_in[0];
  const float* flu = (const float*)d_in[1];
  const float* Wq  = (const float*)d_in[2];
  const float* bq  = (const float*)d_in[3];
  const float* Wk  = (const float*)d_in[4];
  const float* bk  = (const float*)d_in[5];
  const float* Wv  = (const float*)d_in[6];
  const float* bv  = (const float*)d_in[7];
  const float* Wo  = (const float*)d_in[8];
  const float* bo  = (const float*)d_in[9];
  float* out = (float*)d_out;

  char* ws = (char*)d_ws;
  bf16_t* Qb = (bf16_t*)(ws);                 // [2][8][4096][32] = 4 MB
  bf16_t* Kb = (bf16_t*)(ws + (4u << 20));    // 4 MB
  bf16_t* Vb = (bf16_t*)(ws + (8u << 20));    // [2][256][4096]  = 4 MB
  bf16_t* AO = (bf16_t*)(ws + (12u << 20));   // [2][4096][256]  = 4 MB
  bf16_t* Wb = (bf16_t*)(ws + (16u << 20));   // 4 x 65536 bf16  = 512 KB

  cvt_w<<<256, 256, 0, stream>>>(Wq, Wk, Wv, Wo, Wb);
  proj_qkv<<<dim3(64, 8, 2), 256, 0, stream>>>(x, flu,
      Wb, Wb + 65536, Wb + 131072, bq, bk, bv, Qb, Kb, Vb);
  attn_fwd<<<1024, 256, 0, stream>>>(Qb, Kb, Vb, AO);
  proj_out<<<dim3(128, 4, 2), 256, 0, stream>>>(AO, Wb + 196608, bo, out);
}

// Round 21
// 89.603 us; speedup vs baseline: 1.0480x; 1.0480x over previous
//
#include <hip/hip_runtime.h>

typedef __bf16 bf16_t;
typedef bf16_t bf16x8 __attribute__((ext_vector_type(8)));
typedef bf16_t bf16x4 __attribute__((ext_vector_type(4)));
typedef float f32x4 __attribute__((ext_vector_type(4)));

#define HW 4096
#define NC 256

__device__ __forceinline__ f32x4 mfma16(bf16x8 a, bf16x8 b, f32x4 c) {
  return __builtin_amdgcn_mfma_f32_16x16x32_bf16(a, b, c, 0, 0, 0);
}

// pack 8 f32 -> bf16x8 via v_cvt_pk_bf16_f32 (4 insts; elem order preserved)
__device__ __forceinline__ bf16x8 pack_bf16x8(float a0, float a1, float a2, float a3,
                                              float a4, float a5, float a6, float a7) {
  union { unsigned int u[4]; bf16x8 v; } r;
  asm("v_cvt_pk_bf16_f32 %0, %1, %2" : "=v"(r.u[0]) : "v"(a0), "v"(a1));
  asm("v_cvt_pk_bf16_f32 %0, %1, %2" : "=v"(r.u[1]) : "v"(a2), "v"(a3));
  asm("v_cvt_pk_bf16_f32 %0, %1, %2" : "=v"(r.u[2]) : "v"(a4), "v"(a5));
  asm("v_cvt_pk_bf16_f32 %0, %1, %2" : "=v"(r.u[3]) : "v"(a6), "v"(a7));
  return r.v;
}

// K-tile LDS bank swizzle: slot' = slot ^ swz(row) (verified conflict-free
// for both the staging writes and the permuted reads).
__device__ __forceinline__ int kswz(int m) {
  return ((m >> 1) & 1) | (((m >> 3) & 1) << 1);
}

// ---------------- kernel 0: convert weights fp32 -> bf16 ----------------
__global__ void cvt_w(const float* __restrict__ wq, const float* __restrict__ wk,
                      const float* __restrict__ wv, const float* __restrict__ wo,
                      bf16_t* __restrict__ dst) {
  int i = blockIdx.x * 256 + threadIdx.x;           // 65536 threads
  dst[i]          = (bf16_t)wq[i];
  dst[65536 + i]  = (bf16_t)wk[i];
  dst[131072 + i] = (bf16_t)wv[i];
  dst[196608 + i] = (bf16_t)wo[i];
}

// ---------------- kernel 1: QKV projection (double-buffered + prefetch) ----
// grid (64 p-tiles, 4 o-tiles, 2 b), block 256 (4 waves)
// Q,K stored [b][h][p][d] bf16 (Q pre-scaled by dk^-0.5 * log2(e)); V stored [b][o][p] bf16.
// Per c0-iter: prefetch next x/flu tile into regs right after the barrier
// (hidden under this tile's MFMAs), store to alternate LDS buffer, ONE
// barrier/iter. Indexing identical to the proven single-buffer version.
__global__ __launch_bounds__(256) void proj_qkv(
    const float* __restrict__ x, const float* __restrict__ flu,
    const bf16_t* __restrict__ Wq, const bf16_t* __restrict__ Wk,
    const bf16_t* __restrict__ Wv,
    const float* __restrict__ bq, const float* __restrict__ bk,
    const float* __restrict__ bv,
    bf16_t* __restrict__ Qb, bf16_t* __restrict__ Kb, bf16_t* __restrict__ Vb) {
  const int p0 = blockIdx.x * 64;
  const int o0 = blockIdx.y * 64;
  const int b  = blockIdx.z;
  const int tid = threadIdx.x;
  const int w = tid >> 6;
  const int lane = tid & 63;
  const int ln = lane & 15, hi = lane >> 4;

  __shared__ __align__(16) bf16_t lds_f[2][64][40];   // [buf][p][c], pad 32->40
  __shared__ __align__(16) bf16_t lds_x[2][64][40];

  f32x4 accQ[4] = {}, accK[4] = {}, accV[4] = {};

  const int cl = tid >> 3;          // 0..31 local c
  const int pp = (tid & 7) * 4;     // 0..28 local p
  const float* fbase = flu + (size_t)b * NC * HW + p0;
  const float* xbase = x   + (size_t)b * NC * HW + p0;

  // prologue: load + store tile for c0 = 0 into buf 0
  float4 fa, fb, xa, xb;
  {
    const float* fr = fbase + (size_t)cl * HW;
    const float* xr = xbase + (size_t)cl * HW;
    fa = *(const float4*)(fr + pp);
    fb = *(const float4*)(fr + pp + 32);
    xa = *(const float4*)(xr + pp);
    xb = *(const float4*)(xr + pp + 32);
  }
#define STORE_TILE(B)                                                        \
  {                                                                          \
    lds_f[B][pp + 0][cl] = (bf16_t)fa.x;  lds_f[B][pp + 1][cl] = (bf16_t)fa.y;  \
    lds_f[B][pp + 2][cl] = (bf16_t)fa.z;  lds_f[B][pp + 3][cl] = (bf16_t)fa.w;  \
    lds_f[B][pp + 32][cl] = (bf16_t)fb.x; lds_f[B][pp + 33][cl] = (bf16_t)fb.y; \
    lds_f[B][pp + 34][cl] = (bf16_t)fb.z; lds_f[B][pp + 35][cl] = (bf16_t)fb.w; \
    lds_x[B][pp + 0][cl] = (bf16_t)xa.x;  lds_x[B][pp + 1][cl] = (bf16_t)xa.y;  \
    lds_x[B][pp + 2][cl] = (bf16_t)xa.z;  lds_x[B][pp + 3][cl] = (bf16_t)xa.w;  \
    lds_x[B][pp + 32][cl] = (bf16_t)xb.x; lds_x[B][pp + 33][cl] = (bf16_t)xb.y; \
    lds_x[B][pp + 34][cl] = (bf16_t)xb.z; lds_x[B][pp + 35][cl] = (bf16_t)xb.w; \
  }
  STORE_TILE(0);
  __syncthreads();

#pragma unroll
  for (int it = 0; it < 8; ++it) {
    const int cur = it & 1;
    const int c0 = it * 32;
    if (it < 7) {  // prefetch next tile (hidden under compute)
      const float* fr = fbase + (size_t)(c0 + 32 + cl) * HW;
      const float* xr = xbase + (size_t)(c0 + 32 + cl) * HW;
      fa = *(const float4*)(fr + pp);
      fb = *(const float4*)(fr + pp + 32);
      xa = *(const float4*)(xr + pp);
      xb = *(const float4*)(xr + pp + 32);
    }

    bf16x8 af = *(const bf16x8*)&lds_f[cur][w * 16 + ln][hi * 8];
    bf16x8 ax = *(const bf16x8*)&lds_x[cur][w * 16 + ln][hi * 8];
    bf16x8 awv = *(const bf16x8*)(Wv + (size_t)(o0 + w * 16 + ln) * NC + c0 + hi * 8);
#pragma unroll
    for (int t = 0; t < 4; ++t) {
      bf16x8 bwq = *(const bf16x8*)(Wq + (size_t)(o0 + t * 16 + ln) * NC + c0 + hi * 8);
      accQ[t] = mfma16(af, bwq, accQ[t]);
      bf16x8 bwk = *(const bf16x8*)(Wk + (size_t)(o0 + t * 16 + ln) * NC + c0 + hi * 8);
      accK[t] = mfma16(ax, bwk, accK[t]);
      bf16x8 bx = *(const bf16x8*)&lds_x[cur][t * 16 + ln][hi * 8];
      accV[t] = mfma16(awv, bx, accV[t]);
    }

    if (it < 7) {
      STORE_TILE(cur ^ 1);
      __syncthreads();
    }
  }
#undef STORE_TILE

  // dk^-0.5 * log2(e): exp2-domain logits
  const float scale = 0.17677669529663687f * 1.4426950408889634f;
#pragma unroll
  for (int t = 0; t < 4; ++t) {
    int o = o0 + t * 16 + ln;
    int h = o >> 5, d = o & 31;
    float bqv = bq[o], bkv = bk[o];
#pragma unroll
    for (int r = 0; r < 4; ++r) {
      int p = p0 + w * 16 + hi * 4 + r;
      size_t idx = (((size_t)(b * 8 + h)) * HW + p) * 32 + d;
      Qb[idx] = (bf16_t)((accQ[t][r] + bqv) * scale);
      Kb[idx] = (bf16_t)(accK[t][r] + bkv);
    }
  }
#pragma unroll
  for (int t = 0; t < 4; ++t) {
    int p = p0 + t * 16 + ln;
#pragma unroll
    for (int r = 0; r < 4; ++r) {
      int o = o0 + w * 16 + hi * 4 + r;
      Vb[((size_t)b * NC + o) * HW + p] = (bf16_t)(accV[t][r] + bv[o]);
    }
  }
}

// ---------------- kernel 2: flash attention (in-block split-K, proven) ----
// Block = 4 waves / 64 q: half = w>>1 selects keys 0..2047 / 2048..4095;
// wq = w&1 selects q-subtile. Per-half K/V LDS staging; exact merge via
// LDS (no-max softmax => plain fp32 add). grid 1024 XCD-swizzled.
__global__ __launch_bounds__(256, 4) void attn_fwd(
    const bf16_t* __restrict__ Qb, const bf16_t* __restrict__ Kb,
    const bf16_t* __restrict__ Vb, bf16_t* __restrict__ AO) {
  // bijective XCD swizzle: 1024 blocks, each XCD gets 128 contiguous lids = 2 bh
  const int fid = blockIdx.x;
  const int lid = (fid & 7) * 128 + (fid >> 3);
  const int q0 = (lid & 63) * 64;
  const int bh = lid >> 6;
  const int b = bh >> 3, h = bh & 7;
  const int tid = threadIdx.x;
  const int w = tid >> 6, lane = tid & 63;
  const int half = w >> 1, wq = w & 1;
  const int ln = lane & 15, hi = lane >> 4;
  const int tid_h = tid & 127;

  __shared__ __align__(16) bf16_t Kt[2][2][2048];   // [half][buf][m*32+d'], swz
  __shared__ __align__(16) bf16_t Vt[2][2][2048];   // [half][buf][d*64+m'], swz

  const bf16_t* Qh = Qb + (size_t)bh * HW * 32;
  const bf16_t* Kh = Kb + (size_t)bh * HW * 32;
  const bf16_t* Vh = Vb + ((size_t)b * NC + h * 32) * HW;

  // B-frags of Q^T: lane holds Q[q0 + wq*32 + g*16 + ln][hi*8..+7]
  const int qb = q0 + wq * 32;
  const bf16x8 qf0 = *(const bf16x8*)(Qh + (size_t)(qb + ln) * 32 + hi * 8);
  const bf16x8 qf1 = *(const bf16x8*)(Qh + (size_t)(qb + 16 + ln) * 32 + hi * 8);

  f32x4 O[2][2] = {};           // O^T accum [g][dt], lane owns q-col ln
  f32x4 Lacc0 = {}, Lacc1 = {}; // ones-row denominators per g
  const bf16_t one = (bf16_t)1.0f;
  const bf16x8 ones = {one, one, one, one, one, one, one, one};

  // K staging (128 threads/half, 2x16B): K tile [64][32], swizzled slots
  const int kr = tid_h >> 1, ksp = (tid_h & 1) * 2;
  const int kofs0 = kr * 32 + ((ksp ^ kswz(kr)) * 8);
  const int kofs1 = kr * 32 + (((ksp + 1) ^ kswz(kr)) * 8);
  const bf16_t* kgp = Kh + (size_t)(half * 2048 + kr) * 32 + ksp * 8;

  // V staging (128 threads/half, 2x16B): V^T tile [32][64]
  const int vr = tid_h >> 2, vsp = (tid_h & 3) * 2;
  const int vofs0 = vr * 64 + ((vsp ^ (vr & 7)) * 8);
  const int vofs1 = vr * 64 + (((vsp + 1) ^ (vr & 7)) * 8);
  const bf16_t* vgp = Vh + (size_t)vr * HW + half * 2048 + vsp * 8;

  // permuted K read offsets (proven conflict-free under kswz)
  int kread[2][2];
  {
    const int F0 = 8 * (ln >> 2) + (ln & 3);
#pragma unroll
    for (int ch = 0; ch < 2; ++ch) {
#pragma unroll
      for (int j = 0; j < 2; ++j) {
        int row = ch * 32 + F0 + 4 * j;
        kread[ch][j] = row * 32 + ((hi ^ kswz(row)) * 8);
      }
    }
  }
  int vread[2][2];
#pragma unroll
  for (int dt = 0; dt < 2; ++dt)
#pragma unroll
    for (int ch = 0; ch < 2; ++ch)
      vread[dt][ch] = (dt * 16 + ln) * 64 + (((ch * 4 + hi) ^ (ln & 7)) * 8);

  // prologue: tile 0 staging regs
  bf16x8 kstA0 = *(const bf16x8*)kgp;
  bf16x8 kstA1 = *(const bf16x8*)(kgp + 8);
  bf16x8 vstA0 = *(const bf16x8*)vgp;
  bf16x8 vstA1 = *(const bf16x8*)(vgp + 8);
  bf16x8 kstB0, kstB1, vstB0, vstB1;

  auto compute = [&](const bf16_t* K_, const bf16_t* V_) {
    __builtin_amdgcn_s_setprio(1);
#pragma unroll
    for (int ch = 0; ch < 2; ++ch) {
      bf16x8 kf0 = *(const bf16x8*)&K_[kread[ch][0]];
      bf16x8 kf1 = *(const bf16x8*)&K_[kread[ch][1]];
      f32x4 z = {};
      f32x4 Sa0 = mfma16(kf0, qf0, z);
      f32x4 Sa1 = mfma16(kf1, qf0, z);
      f32x4 Sb0 = mfma16(kf0, qf1, z);
      f32x4 Sb1 = mfma16(kf1, qf1, z);
      float a0 = __builtin_amdgcn_exp2f(Sa0[0]), a1 = __builtin_amdgcn_exp2f(Sa0[1]);
      float a2 = __builtin_amdgcn_exp2f(Sa0[2]), a3 = __builtin_amdgcn_exp2f(Sa0[3]);
      float a4 = __builtin_amdgcn_exp2f(Sa1[0]), a5 = __builtin_amdgcn_exp2f(Sa1[1]);
      float a6 = __builtin_amdgcn_exp2f(Sa1[2]), a7 = __builtin_amdgcn_exp2f(Sa1[3]);
      float b0 = __builtin_amdgcn_exp2f(Sb0[0]), b1 = __builtin_amdgcn_exp2f(Sb0[1]);
      float b2 = __builtin_amdgcn_exp2f(Sb0[2]), b3 = __builtin_amdgcn_exp2f(Sb0[3]);
      float b4 = __builtin_amdgcn_exp2f(Sb1[0]), b5 = __builtin_amdgcn_exp2f(Sb1[1]);
      float b6 = __builtin_amdgcn_exp2f(Sb1[2]), b7 = __builtin_amdgcn_exp2f(Sb1[3]);
      bf16x8 pa = pack_bf16x8(a0, a1, a2, a3, a4, a5, a6, a7);
      bf16x8 pb = pack_bf16x8(b0, b1, b2, b3, b4, b5, b6, b7);
      Lacc0 = mfma16(ones, pa, Lacc0);
      Lacc1 = mfma16(ones, pb, Lacc1);
#pragma unroll
      for (int dt = 0; dt < 2; ++dt) {
        bf16x8 vf = *(const bf16x8*)&V_[vread[dt][ch]];
        O[0][dt] = mfma16(vf, pa, O[0][dt]);
        O[1][dt] = mfma16(vf, pb, O[1][dt]);
      }
    }
    __builtin_amdgcn_s_setprio(0);
  };

  for (int t = 0; t < 16; ++t) {
    // ---- even tile 2t ----
    {
      bf16_t* K0 = &Kt[half][0][0];
      bf16_t* V0 = &Vt[half][0][0];
      *(bf16x8*)&K0[kofs0] = kstA0;
      *(bf16x8*)&K0[kofs1] = kstA1;
      *(bf16x8*)&V0[vofs0] = vstA0;
      *(bf16x8*)&V0[vofs1] = vstA1;
    }
    __syncthreads();
    {  // prefetch tile 2t+1 (always valid: <= 31)
      kstB0 = *(const bf16x8*)(kgp + (size_t)(2 * t + 1) * 2048);
      kstB1 = *(const bf16x8*)(kgp + (size_t)(2 * t + 1) * 2048 + 8);
      vstB0 = *(const bf16x8*)(vgp + (2 * t + 1) * 64);
      vstB1 = *(const bf16x8*)(vgp + (2 * t + 1) * 64 + 8);
    }
    compute(&Kt[half][0][0], &Vt[half][0][0]);
    // ---- odd tile 2t+1 ----
    {
      bf16_t* K1 = &Kt[half][1][0];
      bf16_t* V1 = &Vt[half][1][0];
      *(bf16x8*)&K1[kofs0] = kstB0;
      *(bf16x8*)&K1[kofs1] = kstB1;
      *(bf16x8*)&V1[vofs0] = vstB0;
      *(bf16x8*)&V1[vofs1] = vstB1;
    }
    __syncthreads();
    if (t < 15) {  // prefetch tile 2t+2
      kstA0 = *(const bf16x8*)(kgp + (size_t)(2 * t + 2) * 2048);
      kstA1 = *(const bf16x8*)(kgp + (size_t)(2 * t + 2) * 2048 + 8);
      vstA0 = *(const bf16x8*)(vgp + (2 * t + 2) * 64);
      vstA1 = *(const bf16x8*)(vgp + (2 * t + 2) * 64 + 8);
    }
    compute(&Kt[half][1][0], &Vt[half][1][0]);
  }

  // ---- split-K merge (exact: no-max softmax => plain fp32 add) ----
  __syncthreads();                       // all K/V use done; safe to alias Kt
  float* MO = (float*)&Kt[0][0][0];      // [64 q][32 d], swizzled 4-slot cols
  float* ML = MO + 2048;                 // [2 wq][2 g][16 ln]
  if (half == 1) {
#pragma unroll
    for (int g = 0; g < 2; ++g) {
      int q = wq * 32 + g * 16 + ln;
#pragma unroll
      for (int dt = 0; dt < 2; ++dt) {
        int slot = dt * 4 + hi;
        *(f32x4*)&MO[q * 32 + ((slot ^ (ln & 7)) * 4)] = O[g][dt];
      }
    }
    if (hi == 0) { ML[(wq * 2 + 0) * 16 + ln] = Lacc0[0];
                   ML[(wq * 2 + 1) * 16 + ln] = Lacc1[0]; }
  }
  __syncthreads();
  if (half == 0) {
#pragma unroll
    for (int g = 0; g < 2; ++g) {
      int q = wq * 32 + g * 16 + ln;
      float l = (g ? Lacc1[0] : Lacc0[0]) + ML[(wq * 2 + g) * 16 + ln];
      float inv = 1.0f / l;
      const int p = q0 + q;
#pragma unroll
      for (int dt = 0; dt < 2; ++dt) {
        int slot = dt * 4 + hi;
        f32x4 o4 = O[g][dt] + *(const f32x4*)&MO[q * 32 + ((slot ^ (ln & 7)) * 4)];
        bf16x4 ov = {(bf16_t)(o4[0] * inv), (bf16_t)(o4[1] * inv),
                     (bf16_t)(o4[2] * inv), (bf16_t)(o4[3] * inv)};
        *(bf16x4*)(AO + ((size_t)b * HW + p) * NC + h * 32 + dt * 16 + hi * 4) = ov;
      }
    }
  }
}

// ---------------- kernel 3: output projection (register double-buffer) ----
// grid (64 p-tiles, 4 o-tiles, 2 b), block 256. Next c0's aw + 4 bfr global
// loads are issued while the current set's MFMAs execute (2x unrolled).
__global__ __launch_bounds__(256) void proj_out(
    const bf16_t* __restrict__ AO, const bf16_t* __restrict__ Wo,
    const float* __restrict__ bo, float* __restrict__ out) {
  const int p0 = blockIdx.x * 64;
  const int o0 = blockIdx.y * 64;
  const int b  = blockIdx.z;
  const int tid = threadIdx.x;
  const int w = tid >> 6, lane = tid & 63;
  const int ln = lane & 15, hi = lane >> 4;

  const bf16_t* awp = Wo + (size_t)(o0 + w * 16 + ln) * NC + hi * 8;
  const bf16_t* bp0 = AO + ((size_t)b * HW + p0 + ln) * NC + hi * 8;

  f32x4 acc[4] = {};
  bf16x8 awA, awB, bA[4], bB[4];
  awA = *(const bf16x8*)awp;
#pragma unroll
  for (int t = 0; t < 4; ++t) bA[t] = *(const bf16x8*)(bp0 + (size_t)(t * 16) * NC);

#pragma unroll
  for (int it = 0; it < 8; it += 2) {
    {  // prefetch set B (c0 = (it+1)*32)
      int c1 = (it + 1) * 32;
      awB = *(const bf16x8*)(awp + c1);
#pragma unroll
      for (int t = 0; t < 4; ++t) bB[t] = *(const bf16x8*)(bp0 + (size_t)(t * 16) * NC + c1);
    }
#pragma unroll
    for (int t = 0; t < 4; ++t) acc[t] = mfma16(awA, bA[t], acc[t]);
    if (it + 2 < 8) {  // prefetch set A (c0 = (it+2)*32)
      int c2 = (it + 2) * 32;
      awA = *(const bf16x8*)(awp + c2);
#pragma unroll
      for (int t = 0; t < 4; ++t) bA[t] = *(const bf16x8*)(bp0 + (size_t)(t * 16) * NC + c2);
    }
#pragma unroll
    for (int t = 0; t < 4; ++t) acc[t] = mfma16(awB, bB[t], acc[t]);
  }

#pragma unroll
  for (int t = 0; t < 4; ++t) {
#pragma unroll
    for (int r = 0; r < 4; ++r) {
      int o = o0 + w * 16 + hi * 4 + r;
      out[((size_t)b * NC + o) * HW + p0 + t * 16 + ln] = acc[t][r] + bo[o];
    }
  }
}

// ---------------- launch ----------------
extern "C" void kernel_launch(void* const* d_in, const int* in_sizes, int n_in,
                              void* d_out, int out_size, void* d_ws, size_t ws_size,
                              hipStream_t stream) {
  const float* x   = (const float*)d_in[0];
  const float* flu = (const float*)d_in[1];
  const float* Wq  = (const float*)d_in[2];
  const float* bq  = (const float*)d_in[3];
  const float* Wk  = (const float*)d_in[4];
  const float* bk  = (const float*)d_in[5];
  const float* Wv  = (const float*)d_in[6];
  const float* bv  = (const float*)d_in[7];
  const float* Wo  = (const float*)d_in[8];
  const float* bo  = (const float*)d_in[9];
  float* out = (float*)d_out;

  char* ws = (char*)d_ws;
  bf16_t* Qb = (bf16_t*)(ws);                 // [2][8][4096][32] = 4 MB
  bf16_t* Kb = (bf16_t*)(ws + (4u << 20));    // 4 MB
  bf16_t* Vb = (bf16_t*)(ws + (8u << 20));    // [2][256][4096]  = 4 MB
  bf16_t* AO = (bf16_t*)(ws + (12u << 20));   // [2][4096][256]  = 4 MB
  bf16_t* Wb = (bf16_t*)(ws + (16u << 20));   // 4 x 65536 bf16  = 512 KB

  cvt_w<<<256, 256, 0, stream>>>(Wq, Wk, Wv, Wo, Wb);
  proj_qkv<<<dim3(64, 4, 2), 256, 0, stream>>>(x, flu,
      Wb, Wb + 65536, Wb + 131072, bq, bk, bv, Qb, Kb, Vb);
  attn_fwd<<<1024, 256, 0, stream>>>(Qb, Kb, Vb, AO);
  proj_out<<<dim3(64, 4, 2), 256, 0, stream>>>(AO, Wb + 196608, bo, out);
}

// Round 22
// 89.009 us; speedup vs baseline: 1.0550x; 1.0067x over previous
//
#include <hip/hip_runtime.h>

typedef __bf16 bf16_t;
typedef bf16_t bf16x8 __attribute__((ext_vector_type(8)));
typedef bf16_t bf16x4 __attribute__((ext_vector_type(4)));
typedef float f32x4 __attribute__((ext_vector_type(4)));

#define HW 4096
#define NC 256

__device__ __forceinline__ f32x4 mfma16(bf16x8 a, bf16x8 b, f32x4 c) {
  return __builtin_amdgcn_mfma_f32_16x16x32_bf16(a, b, c, 0, 0, 0);
}

// pack 8 f32 -> bf16x8 via v_cvt_pk_bf16_f32 (4 insts; elem order preserved)
__device__ __forceinline__ bf16x8 pack_bf16x8(float a0, float a1, float a2, float a3,
                                              float a4, float a5, float a6, float a7) {
  union { unsigned int u[4]; bf16x8 v; } r;
  asm("v_cvt_pk_bf16_f32 %0, %1, %2" : "=v"(r.u[0]) : "v"(a0), "v"(a1));
  asm("v_cvt_pk_bf16_f32 %0, %1, %2" : "=v"(r.u[1]) : "v"(a2), "v"(a3));
  asm("v_cvt_pk_bf16_f32 %0, %1, %2" : "=v"(r.u[2]) : "v"(a4), "v"(a5));
  asm("v_cvt_pk_bf16_f32 %0, %1, %2" : "=v"(r.u[3]) : "v"(a6), "v"(a7));
  return r.v;
}

// K-tile LDS bank swizzle: slot' = slot ^ swz(row) (verified conflict-free
// for both the staging writes and the permuted reads).
__device__ __forceinline__ int kswz(int m) {
  return ((m >> 1) & 1) | (((m >> 3) & 1) << 1);
}

// ---------------- kernel 0: convert weights fp32 -> bf16 ----------------
__global__ void cvt_w(const float* __restrict__ wq, const float* __restrict__ wk,
                      const float* __restrict__ wv, const float* __restrict__ wo,
                      bf16_t* __restrict__ dst) {
  int i = blockIdx.x * 256 + threadIdx.x;           // 65536 threads
  dst[i]          = (bf16_t)wq[i];
  dst[65536 + i]  = (bf16_t)wk[i];
  dst[131072 + i] = (bf16_t)wv[i];
  dst[196608 + i] = (bf16_t)wo[i];
}

// ---------------- kernel 1: QKV projection ----------------
// grid (64 p-tiles, 4 o-tiles, 2 b), block 256 (4 waves)
// Double-buffered LDS for x/flu (R18) PLUS register double-buffer for the
// weight stream: 9 bf16x8 fragments (4 Wq + 4 Wk + 1 Wv) prefetched one
// iter ahead so no global load sits on the MFMA critical path.
__global__ __launch_bounds__(256) void proj_qkv(
    const float* __restrict__ x, const float* __restrict__ flu,
    const bf16_t* __restrict__ Wq, const bf16_t* __restrict__ Wk,
    const bf16_t* __restrict__ Wv,
    const float* __restrict__ bq, const float* __restrict__ bk,
    const float* __restrict__ bv,
    bf16_t* __restrict__ Qb, bf16_t* __restrict__ Kb, bf16_t* __restrict__ Vb) {
  const int p0 = blockIdx.x * 64;
  const int o0 = blockIdx.y * 64;
  const int b  = blockIdx.z;
  const int tid = threadIdx.x;
  const int w = tid >> 6;
  const int lane = tid & 63;
  const int ln = lane & 15, hi = lane >> 4;

  __shared__ __align__(16) bf16_t lds_f[2][64][40];   // [buf][p][c], pad 32->40
  __shared__ __align__(16) bf16_t lds_x[2][64][40];

  f32x4 accQ[4] = {}, accK[4] = {}, accV[4] = {};

  const int cl = tid >> 3;          // 0..31 local c
  const int pp = (tid & 7) * 4;     // 0..28 local p
  const float* fbase = flu + (size_t)b * NC * HW + p0;
  const float* xbase = x   + (size_t)b * NC * HW + p0;

  // per-thread weight fragment base pointers (row fixed, c advances)
  const bf16_t* wqp = Wq + (size_t)(o0 + ln) * NC + hi * 8;       // + t*16*NC + c0
  const bf16_t* wkp = Wk + (size_t)(o0 + ln) * NC + hi * 8;
  const bf16_t* wvp = Wv + (size_t)(o0 + w * 16 + ln) * NC + hi * 8;

  // prologue: x/flu tile 0 + weight set 0
  float4 fa, fb, xa, xb;
  {
    const float* fr = fbase + (size_t)cl * HW;
    const float* xr = xbase + (size_t)cl * HW;
    fa = *(const float4*)(fr + pp);
    fb = *(const float4*)(fr + pp + 32);
    xa = *(const float4*)(xr + pp);
    xb = *(const float4*)(xr + pp + 32);
  }
  bf16x8 wqP[2][4], wkP[2][4], wvP[2];
#pragma unroll
  for (int t = 0; t < 4; ++t) {
    wqP[0][t] = *(const bf16x8*)(wqp + (size_t)(t * 16) * NC);
    wkP[0][t] = *(const bf16x8*)(wkp + (size_t)(t * 16) * NC);
  }
  wvP[0] = *(const bf16x8*)wvp;

#define STORE_TILE(B)                                                        \
  {                                                                          \
    lds_f[B][pp + 0][cl] = (bf16_t)fa.x;  lds_f[B][pp + 1][cl] = (bf16_t)fa.y;  \
    lds_f[B][pp + 2][cl] = (bf16_t)fa.z;  lds_f[B][pp + 3][cl] = (bf16_t)fa.w;  \
    lds_f[B][pp + 32][cl] = (bf16_t)fb.x; lds_f[B][pp + 33][cl] = (bf16_t)fb.y; \
    lds_f[B][pp + 34][cl] = (bf16_t)fb.z; lds_f[B][pp + 35][cl] = (bf16_t)fb.w; \
    lds_x[B][pp + 0][cl] = (bf16_t)xa.x;  lds_x[B][pp + 1][cl] = (bf16_t)xa.y;  \
    lds_x[B][pp + 2][cl] = (bf16_t)xa.z;  lds_x[B][pp + 3][cl] = (bf16_t)xa.w;  \
    lds_x[B][pp + 32][cl] = (bf16_t)xb.x; lds_x[B][pp + 33][cl] = (bf16_t)xb.y; \
    lds_x[B][pp + 34][cl] = (bf16_t)xb.z; lds_x[B][pp + 35][cl] = (bf16_t)xb.w; \
  }
  STORE_TILE(0);
  __syncthreads();

#pragma unroll
  for (int it = 0; it < 8; ++it) {
    const int cur = it & 1;
    const int nxt = cur ^ 1;
    const int c0 = it * 32;
    if (it < 7) {  // prefetch next x/flu tile (hidden under compute)
      const float* fr = fbase + (size_t)(c0 + 32 + cl) * HW;
      const float* xr = xbase + (size_t)(c0 + 32 + cl) * HW;
      fa = *(const float4*)(fr + pp);
      fb = *(const float4*)(fr + pp + 32);
      xa = *(const float4*)(xr + pp);
      xb = *(const float4*)(xr + pp + 32);
      // prefetch next weight set (9 L2-resident fragments)
#pragma unroll
      for (int t = 0; t < 4; ++t) {
        wqP[nxt][t] = *(const bf16x8*)(wqp + (size_t)(t * 16) * NC + c0 + 32);
        wkP[nxt][t] = *(const bf16x8*)(wkp + (size_t)(t * 16) * NC + c0 + 32);
      }
      wvP[nxt] = *(const bf16x8*)(wvp + c0 + 32);
    }

    bf16x8 af = *(const bf16x8*)&lds_f[cur][w * 16 + ln][hi * 8];
    bf16x8 ax = *(const bf16x8*)&lds_x[cur][w * 16 + ln][hi * 8];
#pragma unroll
    for (int t = 0; t < 4; ++t) {
      accQ[t] = mfma16(af, wqP[cur][t], accQ[t]);
      accK[t] = mfma16(ax, wkP[cur][t], accK[t]);
      bf16x8 bx = *(const bf16x8*)&lds_x[cur][t * 16 + ln][hi * 8];
      accV[t] = mfma16(wvP[cur], bx, accV[t]);
    }

    if (it < 7) {
      STORE_TILE(nxt);
      __syncthreads();
    }
  }
#undef STORE_TILE

  // dk^-0.5 * log2(e): exp2-domain logits
  const float scale = 0.17677669529663687f * 1.4426950408889634f;
#pragma unroll
  for (int t = 0; t < 4; ++t) {
    int o = o0 + t * 16 + ln;
    int h = o >> 5, d = o & 31;
    float bqv = bq[o], bkv = bk[o];
#pragma unroll
    for (int r = 0; r < 4; ++r) {
      int p = p0 + w * 16 + hi * 4 + r;
      size_t idx = (((size_t)(b * 8 + h)) * HW + p) * 32 + d;
      Qb[idx] = (bf16_t)((accQ[t][r] + bqv) * scale);
      Kb[idx] = (bf16_t)(accK[t][r] + bkv);
    }
  }
#pragma unroll
  for (int t = 0; t < 4; ++t) {
    int p = p0 + t * 16 + ln;
#pragma unroll
    for (int r = 0; r < 4; ++r) {
      int o = o0 + w * 16 + hi * 4 + r;
      Vb[((size_t)b * NC + o) * HW + p] = (bf16_t)(accV[t][r] + bv[o]);
    }
  }
}

// ---------------- kernel 2: flash attention (in-block split-K, proven) ----
// Block = 4 waves / 64 q: half = w>>1 selects keys 0..2047 / 2048..4095;
// wq = w&1 selects q-subtile. Per-half K/V LDS staging; exact merge via
// LDS (no-max softmax => plain fp32 add). grid 1024 XCD-swizzled.
__global__ __launch_bounds__(256, 4) void attn_fwd(
    const bf16_t* __restrict__ Qb, const bf16_t* __restrict__ Kb,
    const bf16_t* __restrict__ Vb, bf16_t* __restrict__ AO) {
  // bijective XCD swizzle: 1024 blocks, each XCD gets 128 contiguous lids = 2 bh
  const int fid = blockIdx.x;
  const int lid = (fid & 7) * 128 + (fid >> 3);
  const int q0 = (lid & 63) * 64;
  const int bh = lid >> 6;
  const int b = bh >> 3, h = bh & 7;
  const int tid = threadIdx.x;
  const int w = tid >> 6, lane = tid & 63;
  const int half = w >> 1, wq = w & 1;
  const int ln = lane & 15, hi = lane >> 4;
  const int tid_h = tid & 127;

  __shared__ __align__(16) bf16_t Kt[2][2][2048];   // [half][buf][m*32+d'], swz
  __shared__ __align__(16) bf16_t Vt[2][2][2048];   // [half][buf][d*64+m'], swz

  const bf16_t* Qh = Qb + (size_t)bh * HW * 32;
  const bf16_t* Kh = Kb + (size_t)bh * HW * 32;
  const bf16_t* Vh = Vb + ((size_t)b * NC + h * 32) * HW;

  // B-frags of Q^T: lane holds Q[q0 + wq*32 + g*16 + ln][hi*8..+7]
  const int qb = q0 + wq * 32;
  const bf16x8 qf0 = *(const bf16x8*)(Qh + (size_t)(qb + ln) * 32 + hi * 8);
  const bf16x8 qf1 = *(const bf16x8*)(Qh + (size_t)(qb + 16 + ln) * 32 + hi * 8);

  f32x4 O[2][2] = {};           // O^T accum [g][dt], lane owns q-col ln
  f32x4 Lacc0 = {}, Lacc1 = {}; // ones-row denominators per g
  const bf16_t one = (bf16_t)1.0f;
  const bf16x8 ones = {one, one, one, one, one, one, one, one};

  // K staging (128 threads/half, 2x16B): K tile [64][32], swizzled slots
  const int kr = tid_h >> 1, ksp = (tid_h & 1) * 2;
  const int kofs0 = kr * 32 + ((ksp ^ kswz(kr)) * 8);
  const int kofs1 = kr * 32 + (((ksp + 1) ^ kswz(kr)) * 8);
  const bf16_t* kgp = Kh + (size_t)(half * 2048 + kr) * 32 + ksp * 8;

  // V staging (128 threads/half, 2x16B): V^T tile [32][64]
  const int vr = tid_h >> 2, vsp = (tid_h & 3) * 2;
  const int vofs0 = vr * 64 + ((vsp ^ (vr & 7)) * 8);
  const int vofs1 = vr * 64 + (((vsp + 1) ^ (vr & 7)) * 8);
  const bf16_t* vgp = Vh + (size_t)vr * HW + half * 2048 + vsp * 8;

  // permuted K read offsets (proven conflict-free under kswz)
  int kread[2][2];
  {
    const int F0 = 8 * (ln >> 2) + (ln & 3);
#pragma unroll
    for (int ch = 0; ch < 2; ++ch) {
#pragma unroll
      for (int j = 0; j < 2; ++j) {
        int row = ch * 32 + F0 + 4 * j;
        kread[ch][j] = row * 32 + ((hi ^ kswz(row)) * 8);
      }
    }
  }
  int vread[2][2];
#pragma unroll
  for (int dt = 0; dt < 2; ++dt)
#pragma unroll
    for (int ch = 0; ch < 2; ++ch)
      vread[dt][ch] = (dt * 16 + ln) * 64 + (((ch * 4 + hi) ^ (ln & 7)) * 8);

  // prologue: tile 0 staging regs
  bf16x8 kstA0 = *(const bf16x8*)kgp;
  bf16x8 kstA1 = *(const bf16x8*)(kgp + 8);
  bf16x8 vstA0 = *(const bf16x8*)vgp;
  bf16x8 vstA1 = *(const bf16x8*)(vgp + 8);
  bf16x8 kstB0, kstB1, vstB0, vstB1;

  auto compute = [&](const bf16_t* K_, const bf16_t* V_) {
    __builtin_amdgcn_s_setprio(1);
#pragma unroll
    for (int ch = 0; ch < 2; ++ch) {
      bf16x8 kf0 = *(const bf16x8*)&K_[kread[ch][0]];
      bf16x8 kf1 = *(const bf16x8*)&K_[kread[ch][1]];
      f32x4 z = {};
      f32x4 Sa0 = mfma16(kf0, qf0, z);
      f32x4 Sa1 = mfma16(kf1, qf0, z);
      f32x4 Sb0 = mfma16(kf0, qf1, z);
      f32x4 Sb1 = mfma16(kf1, qf1, z);
      float a0 = __builtin_amdgcn_exp2f(Sa0[0]), a1 = __builtin_amdgcn_exp2f(Sa0[1]);
      float a2 = __builtin_amdgcn_exp2f(Sa0[2]), a3 = __builtin_amdgcn_exp2f(Sa0[3]);
      float a4 = __builtin_amdgcn_exp2f(Sa1[0]), a5 = __builtin_amdgcn_exp2f(Sa1[1]);
      float a6 = __builtin_amdgcn_exp2f(Sa1[2]), a7 = __builtin_amdgcn_exp2f(Sa1[3]);
      float b0 = __builtin_amdgcn_exp2f(Sb0[0]), b1 = __builtin_amdgcn_exp2f(Sb0[1]);
      float b2 = __builtin_amdgcn_exp2f(Sb0[2]), b3 = __builtin_amdgcn_exp2f(Sb0[3]);
      float b4 = __builtin_amdgcn_exp2f(Sb1[0]), b5 = __builtin_amdgcn_exp2f(Sb1[1]);
      float b6 = __builtin_amdgcn_exp2f(Sb1[2]), b7 = __builtin_amdgcn_exp2f(Sb1[3]);
      bf16x8 pa = pack_bf16x8(a0, a1, a2, a3, a4, a5, a6, a7);
      bf16x8 pb = pack_bf16x8(b0, b1, b2, b3, b4, b5, b6, b7);
      Lacc0 = mfma16(ones, pa, Lacc0);
      Lacc1 = mfma16(ones, pb, Lacc1);
#pragma unroll
      for (int dt = 0; dt < 2; ++dt) {
        bf16x8 vf = *(const bf16x8*)&V_[vread[dt][ch]];
        O[0][dt] = mfma16(vf, pa, O[0][dt]);
        O[1][dt] = mfma16(vf, pb, O[1][dt]);
      }
    }
    __builtin_amdgcn_s_setprio(0);
  };

  for (int t = 0; t < 16; ++t) {
    // ---- even tile 2t ----
    {
      bf16_t* K0 = &Kt[half][0][0];
      bf16_t* V0 = &Vt[half][0][0];
      *(bf16x8*)&K0[kofs0] = kstA0;
      *(bf16x8*)&K0[kofs1] = kstA1;
      *(bf16x8*)&V0[vofs0] = vstA0;
      *(bf16x8*)&V0[vofs1] = vstA1;
    }
    __syncthreads();
    {  // prefetch tile 2t+1 (always valid: <= 31)
      kstB0 = *(const bf16x8*)(kgp + (size_t)(2 * t + 1) * 2048);
      kstB1 = *(const bf16x8*)(kgp + (size_t)(2 * t + 1) * 2048 + 8);
      vstB0 = *(const bf16x8*)(vgp + (2 * t + 1) * 64);
      vstB1 = *(const bf16x8*)(vgp + (2 * t + 1) * 64 + 8);
    }
    compute(&Kt[half][0][0], &Vt[half][0][0]);
    // ---- odd tile 2t+1 ----
    {
      bf16_t* K1 = &Kt[half][1][0];
      bf16_t* V1 = &Vt[half][1][0];
      *(bf16x8*)&K1[kofs0] = kstB0;
      *(bf16x8*)&K1[kofs1] = kstB1;
      *(bf16x8*)&V1[vofs0] = vstB0;
      *(bf16x8*)&V1[vofs1] = vstB1;
    }
    __syncthreads();
    if (t < 15) {  // prefetch tile 2t+2
      kstA0 = *(const bf16x8*)(kgp + (size_t)(2 * t + 2) * 2048);
      kstA1 = *(const bf16x8*)(kgp + (size_t)(2 * t + 2) * 2048 + 8);
      vstA0 = *(const bf16x8*)(vgp + (2 * t + 2) * 64);
      vstA1 = *(const bf16x8*)(vgp + (2 * t + 2) * 64 + 8);
    }
    compute(&Kt[half][1][0], &Vt[half][1][0]);
  }

  // ---- split-K merge (exact: no-max softmax => plain fp32 add) ----
  __syncthreads();                       // all K/V use done; safe to alias Kt
  float* MO = (float*)&Kt[0][0][0];      // [64 q][32 d], swizzled 4-slot cols
  float* ML = MO + 2048;                 // [2 wq][2 g][16 ln]
  if (half == 1) {
#pragma unroll
    for (int g = 0; g < 2; ++g) {
      int q = wq * 32 + g * 16 + ln;
#pragma unroll
      for (int dt = 0; dt < 2; ++dt) {
        int slot = dt * 4 + hi;
        *(f32x4*)&MO[q * 32 + ((slot ^ (ln & 7)) * 4)] = O[g][dt];
      }
    }
    if (hi == 0) { ML[(wq * 2 + 0) * 16 + ln] = Lacc0[0];
                   ML[(wq * 2 + 1) * 16 + ln] = Lacc1[0]; }
  }
  __syncthreads();
  if (half == 0) {
#pragma unroll
    for (int g = 0; g < 2; ++g) {
      int q = wq * 32 + g * 16 + ln;
      float l = (g ? Lacc1[0] : Lacc0[0]) + ML[(wq * 2 + g) * 16 + ln];
      float inv = 1.0f / l;
      const int p = q0 + q;
#pragma unroll
      for (int dt = 0; dt < 2; ++dt) {
        int slot = dt * 4 + hi;
        f32x4 o4 = O[g][dt] + *(const f32x4*)&MO[q * 32 + ((slot ^ (ln & 7)) * 4)];
        bf16x4 ov = {(bf16_t)(o4[0] * inv), (bf16_t)(o4[1] * inv),
                     (bf16_t)(o4[2] * inv), (bf16_t)(o4[3] * inv)};
        *(bf16x4*)(AO + ((size_t)b * HW + p) * NC + h * 32 + dt * 16 + hi * 4) = ov;
      }
    }
  }
}

// ---------------- kernel 3: output projection (register double-buffer) ----
// grid (64 p-tiles, 4 o-tiles, 2 b), block 256. Next c0's aw + 4 bfr global
// loads are issued while the current set's MFMAs execute (2x unrolled).
__global__ __launch_bounds__(256) void proj_out(
    const bf16_t* __restrict__ AO, const bf16_t* __restrict__ Wo,
    const float* __restrict__ bo, float* __restrict__ out) {
  const int p0 = blockIdx.x * 64;
  const int o0 = blockIdx.y * 64;
  const int b  = blockIdx.z;
  const int tid = threadIdx.x;
  const int w = tid >> 6, lane = tid & 63;
  const int ln = lane & 15, hi = lane >> 4;

  const bf16_t* awp = Wo + (size_t)(o0 + w * 16 + ln) * NC + hi * 8;
  const bf16_t* bp0 = AO + ((size_t)b * HW + p0 + ln) * NC + hi * 8;

  f32x4 acc[4] = {};
  bf16x8 awA, awB, bA[4], bB[4];
  awA = *(const bf16x8*)awp;
#pragma unroll
  for (int t = 0; t < 4; ++t) bA[t] = *(const bf16x8*)(bp0 + (size_t)(t * 16) * NC);

#pragma unroll
  for (int it = 0; it < 8; it += 2) {
    {  // prefetch set B (c0 = (it+1)*32)
      int c1 = (it + 1) * 32;
      awB = *(const bf16x8*)(awp + c1);
#pragma unroll
      for (int t = 0; t < 4; ++t) bB[t] = *(const bf16x8*)(bp0 + (size_t)(t * 16) * NC + c1);
    }
#pragma unroll
    for (int t = 0; t < 4; ++t) acc[t] = mfma16(awA, bA[t], acc[t]);
    if (it + 2 < 8) {  // prefetch set A (c0 = (it+2)*32)
      int c2 = (it + 2) * 32;
      awA = *(const bf16x8*)(awp + c2);
#pragma unroll
      for (int t = 0; t < 4; ++t) bA[t] = *(const bf16x8*)(bp0 + (size_t)(t * 16) * NC + c2);
    }
#pragma unroll
    for (int t = 0; t < 4; ++t) acc[t] = mfma16(awB, bB[t], acc[t]);
  }

#pragma unroll
  for (int t = 0; t < 4; ++t) {
#pragma unroll
    for (int r = 0; r < 4; ++r) {
      int o = o0 + w * 16 + hi * 4 + r;
      out[((size_t)b * NC + o) * HW + p0 + t * 16 + ln] = acc[t][r] + bo[o];
    }
  }
}

// ---------------- launch ----------------
extern "C" void kernel_launch(void* const* d_in, const int* in_sizes, int n_in,
                              void* d_out, int out_size, void* d_ws, size_t ws_size,
                              hipStream_t stream) {
  const float* x   = (const float*)d_in[0];
  const float* flu = (const float*)d_in[1];
  const float* Wq  = (const float*)d_in[2];
  const float* bq  = (const float*)d_in[3];
  const float* Wk  = (const float*)d_in[4];
  const float* bk  = (const float*)d_in[5];
  const float* Wv  = (const float*)d_in[6];
  const float* bv  = (const float*)d_in[7];
  const float* Wo  = (const float*)d_in[8];
  const float* bo  = (const float*)d_in[9];
  float* out = (float*)d_out;

  char* ws = (char*)d_ws;
  bf16_t* Qb = (bf16_t*)(ws);                 // [2][8][4096][32] = 4 MB
  bf16_t* Kb = (bf16_t*)(ws + (4u << 20));    // 4 MB
  bf16_t* Vb = (bf16_t*)(ws + (8u << 20));    // [2][256][4096]  = 4 MB
  bf16_t* AO = (bf16_t*)(ws + (12u << 20));   // [2][4096][256]  = 4 MB
  bf16_t* Wb = (bf16_t*)(ws + (16u << 20));   // 4 x 65536 bf16  = 512 KB

  cvt_w<<<256, 256, 0, stream>>>(Wq, Wk, Wv, Wo, Wb);
  proj_qkv<<<dim3(64, 4, 2), 256, 0, stream>>>(x, flu,
      Wb, Wb + 65536, Wb + 131072, bq, bk, bv, Qb, Kb, Vb);
  attn_fwd<<<1024, 256, 0, stream>>>(Qb, Kb, Vb, AO);
  proj_out<<<dim3(64, 4, 2), 256, 0, stream>>>(AO, Wb + 196608, bo, out);
}